// Round 19
// baseline (178.466 us; speedup 1.0000x reference)
//
#include <hip/hip_runtime.h>

#define BB 64
#define SS 1024
#define HH 512
#define EE 512
#define VV 32000
#define PP 40

typedef __attribute__((ext_vector_type(8))) __bf16 bf16x8;
typedef __attribute__((ext_vector_type(4))) float f32x4;
typedef __attribute__((ext_vector_type(8))) unsigned short us8_t;
typedef __attribute__((ext_vector_type(4))) unsigned short us4_t;

__device__ inline float fast_tanh(float x) {
    float e = __expf(-2.0f * fabsf(x));
    float t = (1.0f - e) / (1.0f + e);
    return copysignf(t, x);
}
__device__ inline float sigmf(float x) { return 1.0f / (1.0f + __expf(-x)); }

// non-volatile: pure register computation, schedulable/CSE-able (R12 lesson)
__device__ inline unsigned int cvtpk(float lo, float hi) {
    unsigned int r;
    asm("v_cvt_pk_bf16_f32 %0, %1, %2" : "=v"(r) : "v"(lo), "v"(hi));
    return r;
}
__device__ inline us8_t pack8c(float4 x, float4 y) {
    union { unsigned int u[4]; us8_t v; } r;
    r.u[0] = cvtpk(x.x, x.y); r.u[1] = cvtpk(x.z, x.w);
    r.u[2] = cvtpk(y.x, y.y); r.u[3] = cvtpk(y.z, y.w);
    return r.v;
}
__device__ inline us8_t pack8v(f32x4 a, f32x4 b) {
    union { unsigned int u[4]; us8_t v; } r;
    r.u[0] = cvtpk(a[0], a[1]); r.u[1] = cvtpk(a[2], a[3]);
    r.u[2] = cvtpk(b[0], b[1]); r.u[3] = cvtpk(b[2], b[3]);
    return r.v;
}

typedef __attribute__((address_space(1))) const unsigned char gas_t;
typedef __attribute__((address_space(3))) unsigned char las_t;
__device__ inline void gload16(const void* g, void* l) {
    __builtin_amdgcn_global_load_lds((gas_t*)g, (las_t*)l, 16, 0, 0);
}

// ---------------------------------------------------------------------------
// k_pre: 0..63 qs = hidden @ W_s^T; 64..95 W_h->bf16; 96..351 gate;
// 352..359 zero ctx_unnorm (+ block 352 zeros denom).
// ---------------------------------------------------------------------------
__global__ __launch_bounds__(256)
void k_pre(const float* __restrict__ hidden, const float* __restrict__ Ws,
           const float* __restrict__ Wh, const float* __restrict__ pos,
           const float* __restrict__ Wp, const float* __restrict__ bp,
           unsigned short* __restrict__ wh16, float* __restrict__ qs,
           float* __restrict__ gate, float* __restrict__ ctxu,
           float* __restrict__ denom) {
    int blk = blockIdx.x, t = threadIdx.x;
    if (blk < 64) {
        __shared__ float hb[HH];
        int b = blk;
        for (int i = t; i < HH; i += 256) hb[i] = hidden[b * HH + i];
        __syncthreads();
        for (int n = t; n < HH; n += 256) {
            const float* wr = Ws + (size_t)n * HH;
            float acc = 0.0f;
#pragma unroll 4
            for (int k = 0; k < HH; k += 4) {
                float4 w = *(const float4*)(wr + k);
                acc += w.x * hb[k] + w.y * hb[k + 1] + w.z * hb[k + 2] + w.w * hb[k + 3];
            }
            qs[b * HH + n] = acc;
        }
    } else if (blk < 96) {
        int base = (blk - 64) * 8192 + t * 4;
#pragma unroll
        for (int j = 0; j < 8; ++j) {
            int idx = base + j * 1024;
            float4 x = *(const float4*)(Wh + idx);
            union { unsigned int u[2]; us4_t v; } r;
            r.u[0] = cvtpk(x.x, x.y); r.u[1] = cvtpk(x.z, x.w);
            *(us4_t*)(wh16 + idx) = r.v;
        }
    } else if (blk < 352) {
        int idx = (blk - 96) * 256 + t;  // 0..65535 = b*S+s
        const float* pr = pos + (size_t)idx * PP;
        float acc = bp[0];
#pragma unroll
        for (int j = 0; j < 10; ++j) {
            float4 x = *(const float4*)(pr + j * 4);
            acc += x.x * Wp[j * 4] + x.y * Wp[j * 4 + 1] + x.z * Wp[j * 4 + 2] + x.w * Wp[j * 4 + 3];
        }
        gate[idx] = sigmf(acc);
    } else {
        int idx = (blk - 352) * 256 + t;  // ctx_unnorm zero (64*512 f32)
#pragma unroll
        for (int j = 0; j < 16; ++j) ctxu[idx * 16 + j] = 0.0f;
        if (blk == 352 && t < 64) denom[t] = 0.0f;
    }
}

// ---------------------------------------------------------------------------
// k_scores v14 (flash-fused): each block owns COMPLETE scores for 128 s-rows
// (full N=512), then accumulates unnormalized softmax context from its own
// L2-resident enc tile — eliminating k_context's 134MB enc re-read.
// GEMM core = v10 champion scaled x2: 16 waves (4m x 4n), tile 128s x 512n,
// BK=32, 16 K-tiles, both operands via global_load_lds, counted vmcnt(3),
// rule-#21 swizzle (LDS linear dest, pre-swizzled source, XOR read).
// Epilogue: e = exp(gate*score) (bounded, no max-subtract — R4-proven),
// part=e, denom += block-sum(e) [1 atomic], ctxu[h] += sum_s e_s*enc[s,h]
// (enc re-read hits L2: this block just staged those bytes).
// grid 512 = b(64) x sc(8). LDS 98.5KB (m201 precedent for >64KB/WG).
// ---------------------------------------------------------------------------
__global__ __launch_bounds__(1024)
void k_scores(const float* __restrict__ enc,
              const unsigned short* __restrict__ wh16,
              const float* __restrict__ qs, const float* __restrict__ Vw,
              const float* __restrict__ gate, const unsigned char* __restrict__ mask,
              float* __restrict__ part, float* __restrict__ ctxu,
              float* __restrict__ denom) {
    __shared__ float As[2][4096];             // 2 x 16KB [128 r][32 k] f32
    __shared__ unsigned short Bs[2][16384];   // 2 x 32KB [512 r][32 k] bf16
    __shared__ float pbuf[4][128];
    __shared__ float ebuf[128];
    int b = blockIdx.x >> 3, sc = blockIdx.x & 7;
    int s0 = sc * 128;
    int tid = threadIdx.x;
    int w = tid >> 6, lane = tid & 63;
    int wm = w >> 2, wn = w & 3;
    int l15 = lane & 15, lq = lane >> 4;

    float qv[8], vw[8];
#pragma unroll
    for (int nf = 0; nf < 8; ++nf) {
        int n = wn * 128 + nf * 16 + l15;
        qv[nf] = qs[b * HH + n];
        vw[nf] = Vw[n];
    }

    unsigned int colbA = (unsigned int)(((lane & 7) * 16) ^ ((lane >> 3) << 4));
    unsigned int colbB = (unsigned int)(((lane & 3) * 16) ^ (((lane >> 3) & 3) << 4));
    const char* gA0 = (const char*)(enc + (size_t)(b * SS + s0) * HH);
    const char* gB0 = (const char*)wh16;
    int aRowS = w * 8 + (lane >> 3);
    int bRowS = w * 16 + (lane >> 2);    // + p*256
    int ldsOff = w * 1024 + lane * 16;

    int aRowB[2], akey[2], bRowB[8], bkey[8];
#pragma unroll
    for (int mf = 0; mf < 2; ++mf) {
        int r = wm * 32 + mf * 16 + l15;
        aRowB[mf] = r * 128;
        akey[mf] = (r & 7) << 4;
    }
#pragma unroll
    for (int nf = 0; nf < 8; ++nf) {
        int r = wn * 128 + nf * 16 + l15;
        bRowB[nf] = r * 64;
        bkey[nf] = ((r >> 1) & 3) << 4;
    }

    f32x4 acc[2][8];
#pragma unroll
    for (int mf = 0; mf < 2; ++mf)
#pragma unroll
        for (int nf = 0; nf < 8; ++nf) acc[mf][nf] = (f32x4){0.f, 0.f, 0.f, 0.f};

#define STAGE(BUF, KT)                                                          \
    {                                                                           \
        const char* ga = gA0 + (size_t)aRowS * 2048 + (KT) * 128 + colbA;       \
        gload16(ga, (char*)As[BUF] + ldsOff);                                   \
        _Pragma("unroll")                                                       \
        for (int p = 0; p < 2; ++p) {                                           \
            const char* gb = gB0 + (size_t)(p * 256 + bRowS) * 1024 +           \
                             (KT) * 64 + colbB;                                 \
            gload16(gb, (char*)Bs[BUF] + p * 16384 + ldsOff);                   \
        }                                                                       \
    }

#define COMPUTE(BUF)                                                            \
    {                                                                           \
        us8_t af[2], bf[8];                                                     \
        _Pragma("unroll")                                                       \
        for (int mf = 0; mf < 2; ++mf) {                                        \
            const char* pa = (const char*)As[BUF] + aRowB[mf];                  \
            f32x4 a0 = *(const f32x4*)(pa + ((lq * 32) ^ akey[mf]));            \
            f32x4 a1 = *(const f32x4*)(pa + ((lq * 32 + 16) ^ akey[mf]));       \
            af[mf] = pack8v(a0, a1);                                            \
        }                                                                       \
        _Pragma("unroll")                                                       \
        for (int nf = 0; nf < 8; ++nf)                                          \
            bf[nf] = *(const us8_t*)((const char*)Bs[BUF] + bRowB[nf] +         \
                                     ((lq * 16) ^ bkey[nf]));                   \
        _Pragma("unroll")                                                       \
        for (int mf = 0; mf < 2; ++mf)                                          \
            _Pragma("unroll")                                                   \
            for (int nf = 0; nf < 8; ++nf)                                      \
                acc[mf][nf] = __builtin_amdgcn_mfma_f32_16x16x32_bf16(          \
                    __builtin_bit_cast(bf16x8, af[mf]),                         \
                    __builtin_bit_cast(bf16x8, bf[nf]), acc[mf][nf], 0, 0, 0);  \
    }

    STAGE(0, 0);
#pragma unroll
    for (int kt = 0; kt < 16; ++kt) {
        if (kt < 15) {
            STAGE((kt + 1) & 1, kt + 1);
            asm volatile("s_waitcnt vmcnt(3)" ::: "memory");
        } else {
            asm volatile("s_waitcnt vmcnt(0)" ::: "memory");
        }
        __builtin_amdgcn_s_barrier();    // buf[kt&1] fully staged (all waves)
        COMPUTE(kt & 1);
        __builtin_amdgcn_s_barrier();    // all reads done before re-stage
    }
#undef STAGE
#undef COMPUTE

    // ---- scores: p(s) = sum_n Vw[n]*tanh(C + qs[n]) ----
#pragma unroll
    for (int mf = 0; mf < 2; ++mf)
#pragma unroll
        for (int r = 0; r < 4; ++r) {
            float p = 0.0f;
#pragma unroll
            for (int nf = 0; nf < 8; ++nf)
                p += vw[nf] * fast_tanh(acc[mf][nf][r] + qv[nf]);
            p += __shfl_xor(p, 1, 64);
            p += __shfl_xor(p, 2, 64);
            p += __shfl_xor(p, 4, 64);
            p += __shfl_xor(p, 8, 64);
            if (l15 == 0) pbuf[wn][wm * 32 + mf * 16 + lq * 4 + r] = p;
        }
    __syncthreads();

    // ---- e = exp(gated score); write part; block denom ----
    if (tid < 128) {
        int s = s0 + tid;
        float p = pbuf[0][tid] + pbuf[1][tid] + pbuf[2][tid] + pbuf[3][tid];
        float v = mask[b * SS + s] ? -1e30f : p * gate[b * SS + s];
        float e = __expf(v);
        ebuf[tid] = e;
        part[b * SS + s] = e;
    }
    __syncthreads();
    if (tid < 64) {
        float de = ebuf[tid] + ebuf[tid + 64];
#pragma unroll
        for (int off = 1; off < 64; off <<= 1) de += __shfl_xor(de, off, 64);
        if (tid == 0) atomicAdd(&denom[b], de);
    }

    // ---- unnormalized context from L2-resident enc tile ----
    {
        int h = tid & 511, sh = tid >> 9;
        const float* ep = enc + (size_t)(b * SS + s0 + sh * 64) * HH + h;
        const float* eb = &ebuf[sh * 64];
        float sum = 0.0f;
#pragma unroll 4
        for (int j = 0; j < 64; ++j) sum += eb[j] * ep[(size_t)j * HH];
        atomicAdd(&ctxu[b * HH + h], sum);
    }
}

// ---------------------------------------------------------------------------
// k_fin: normalize — attn = part/denom, ctx = ctxu/denom. grid 64 x 256.
// ---------------------------------------------------------------------------
__global__ __launch_bounds__(256)
void k_fin(const float* __restrict__ part, const float* __restrict__ ctxu,
           const float* __restrict__ denom, float* __restrict__ attn,
           float* __restrict__ ctx) {
    int b = blockIdx.x, t = threadIdx.x;
    float inv = 1.0f / denom[b];
    for (int s = t; s < SS; s += 256) attn[b * SS + s] = part[b * SS + s] * inv;
    for (int h = t; h < HH; h += 256) ctx[b * HH + h] = ctxu[b * HH + h] * inv;
}

// ---------------------------------------------------------------------------
// k_build: lstm_in_bf16 = [emb | ctx], h_bf16
// ---------------------------------------------------------------------------
__global__ __launch_bounds__(256)
void k_build(const int* __restrict__ tok, const float* __restrict__ embt,
             const float* __restrict__ ctx, const float* __restrict__ hidden,
             unsigned short* __restrict__ li16, unsigned short* __restrict__ h16v) {
    int b = blockIdx.x, t = threadIdx.x;
    const float* er = embt + (size_t)tok[b] * EE;
    for (int i = 2 * t; i < HH; i += 512) {
        *(unsigned int*)(li16 + b * 1024 + i) = cvtpk(er[i], er[i + 1]);
        *(unsigned int*)(li16 + b * 1024 + 512 + i) = cvtpk(ctx[b * HH + i], ctx[b * HH + i + 1]);
        *(unsigned int*)(h16v + b * HH + i) = cvtpk(hidden[b * HH + i], hidden[b * HH + i + 1]);
    }
}

// ---------------------------------------------------------------------------
// k_gates: gpart[ksl] = lstm_in @ W_ih^T + h @ W_hh^T  (K-slice partials)
// grid 64 = 16 n-tiles(128) x 4 k-slices(384).
// ---------------------------------------------------------------------------
__global__ __launch_bounds__(256)
void k_gates(const unsigned short* __restrict__ li16, const unsigned short* __restrict__ h16v,
             const float* __restrict__ Wih, const float* __restrict__ Whh,
             float* __restrict__ gpart) {
    int nt = blockIdx.x >> 2, ksl = blockIdx.x & 3;
    int wave = threadIdx.x >> 6, lane = threadIdx.x & 63;
    int l15 = lane & 15, lq = lane >> 4, k0 = lq * 8;
    int n0w = nt * 128 + wave * 32;
    f32x4 acc[4][2];
#pragma unroll
    for (int mf = 0; mf < 4; ++mf)
#pragma unroll
        for (int nf = 0; nf < 2; ++nf) acc[mf][nf] = (f32x4){0.f, 0.f, 0.f, 0.f};

    for (int ks = 0; ks < 12; ++ks) {
        int kg = ksl * 384 + ks * 32;
        us8_t af[4];
        if (kg < 1024) {
#pragma unroll
            for (int mf = 0; mf < 4; ++mf)
                af[mf] = *(const us8_t*)(li16 + (mf * 16 + l15) * 1024 + kg + k0);
        } else {
#pragma unroll
            for (int mf = 0; mf < 4; ++mf)
                af[mf] = *(const us8_t*)(h16v + (mf * 16 + l15) * 512 + (kg - 1024) + k0);
        }
#pragma unroll
        for (int nf = 0; nf < 2; ++nf) {
            int n = n0w + nf * 16 + l15;
            us8_t bu;
            if (kg < 1024) {
                const float* wr = Wih + (size_t)n * 1024 + kg + k0;
                bu = pack8c(*(const float4*)wr, *(const float4*)(wr + 4));
            } else {
                const float* wr = Whh + (size_t)n * 512 + (kg - 1024) + k0;
                bu = pack8c(*(const float4*)wr, *(const float4*)(wr + 4));
            }
#pragma unroll
            for (int mf = 0; mf < 4; ++mf)
                acc[mf][nf] = __builtin_amdgcn_mfma_f32_16x16x32_bf16(
                    __builtin_bit_cast(bf16x8, af[mf]),
                    __builtin_bit_cast(bf16x8, bu), acc[mf][nf], 0, 0, 0);
        }
    }
#pragma unroll
    for (int mf = 0; mf < 4; ++mf)
#pragma unroll
        for (int nf = 0; nf < 2; ++nf)
#pragma unroll
            for (int r = 0; r < 4; ++r) {
                int row = mf * 16 + lq * 4 + r;
                int n = n0w + nf * 16 + l15;
                gpart[ksl * (BB * 2048) + row * 2048 + n] = acc[mf][nf][r];
            }
}

// ---------------------------------------------------------------------------
// k_lstm: sum K-slice partials + biases, pointwise cell update
// ---------------------------------------------------------------------------
__global__ __launch_bounds__(512)
void k_lstm(const float* __restrict__ gpart, const float* __restrict__ bih,
            const float* __restrict__ bhh, const float* __restrict__ cell,
            float* __restrict__ oh, float* __restrict__ oc,
            unsigned short* __restrict__ h116) {
    int b = blockIdx.x, t = threadIdx.x;
    float gi = bih[t] + bhh[t];
    float gf = bih[512 + t] + bhh[512 + t];
    float gg = bih[1024 + t] + bhh[1024 + t];
    float go = bih[1536 + t] + bhh[1536 + t];
#pragma unroll
    for (int ksl = 0; ksl < 4; ++ksl) {
        const float* gp = gpart + ksl * (BB * 2048) + b * 2048;
        gi += gp[t];
        gf += gp[512 + t];
        gg += gp[1024 + t];
        go += gp[1536 + t];
    }
    float c0 = cell[b * HH + t];
    float c1 = sigmf(gf) * c0 + sigmf(gi) * fast_tanh(gg);
    float h1 = sigmf(go) * fast_tanh(c1);
    oh[b * HH + t] = h1;
    oc[b * HH + t] = c1;
    h116[b * HH + t] = (unsigned short)(cvtpk(h1, h1) & 0xffffu);
}

// ---------------------------------------------------------------------------
// k_pred: pred = h1 @ W_out^T + b_out  (M=64, N=32000, K=512)
// ---------------------------------------------------------------------------
__global__ __launch_bounds__(512)
void k_pred(const unsigned short* __restrict__ h116, const float* __restrict__ Wout,
            const float* __restrict__ bout, float* __restrict__ pred) {
    int wave = threadIdx.x >> 6, lane = threadIdx.x & 63;
    int l15 = lane & 15, lq = lane >> 4, k0 = lq * 8;
    int n = blockIdx.x * 128 + wave * 16 + l15;
    f32x4 acc[4];
#pragma unroll
    for (int mf = 0; mf < 4; ++mf) acc[mf] = (f32x4){0.f, 0.f, 0.f, 0.f};
    const float* wr = Wout + (size_t)n * HH;
#pragma unroll 4
    for (int ks = 0; ks < 16; ++ks) {
        float4 x = *(const float4*)(wr + ks * 32 + k0);
        float4 y = *(const float4*)(wr + ks * 32 + k0 + 4);
        us8_t bu = pack8c(x, y);
#pragma unroll
        for (int mf = 0; mf < 4; ++mf) {
            us8_t au = *(const us8_t*)(h116 + (mf * 16 + l15) * 512 + ks * 32 + k0);
            acc[mf] = __builtin_amdgcn_mfma_f32_16x16x32_bf16(
                __builtin_bit_cast(bf16x8, au),
                __builtin_bit_cast(bf16x8, bu), acc[mf], 0, 0, 0);
        }
    }
    float bo = bout[n];
#pragma unroll
    for (int mf = 0; mf < 4; ++mf)
#pragma unroll
        for (int r = 0; r < 4; ++r) {
            int row = mf * 16 + lq * 4 + r;
            pred[(size_t)row * VV + n] = acc[mf][r] + bo;
        }
}

// ---------------------------------------------------------------------------
extern "C" void kernel_launch(void* const* d_in, const int* in_sizes, int n_in,
                              void* d_out, int out_size, void* d_ws, size_t ws_size,
                              hipStream_t stream) {
    const int* tok = (const int*)d_in[0];
    const float* hidden = (const float*)d_in[1];
    const float* cell = (const float*)d_in[2];
    const float* enc = (const float*)d_in[3];
    const float* pos = (const float*)d_in[4];
    const unsigned char* mask = (const unsigned char*)d_in[5];
    const float* embt = (const float*)d_in[6];
    const float* Ws = (const float*)d_in[7];
    const float* Wh = (const float*)d_in[8];
    const float* Vw = (const float*)d_in[9];
    const float* Wp = (const float*)d_in[10];
    const float* bp = (const float*)d_in[11];
    const float* Wih = (const float*)d_in[12];
    const float* Whh = (const float*)d_in[13];
    const float* bih = (const float*)d_in[14];
    const float* bhh = (const float*)d_in[15];
    const float* Wout = (const float*)d_in[16];
    const float* bout = (const float*)d_in[17];

    float* out = (float*)d_out;
    float* pred = out;                  // 64*32000
    float* out_h = out + 2048000;       // 64*512
    float* out_c = out + 2080768;       // 64*512
    float* attn = out + 2113536;        // 64*1024

    char* wsb = (char*)d_ws;
    unsigned short* wh16 = (unsigned short*)(wsb);                 // 512KB @0
    float* qs = (float*)(wsb + (512 << 10));                       // 128KB
    float* gate = (float*)(wsb + (640 << 10));                     // 256KB
    float* part = (float*)(wsb + (896 << 10));                     // 256KB (e values)
    float* ctxu = (float*)(wsb + (1152 << 10));                    // 128KB
    float* ctx = (float*)(wsb + (1280 << 10));                     // 128KB
    float* denom = (float*)(wsb + (1408 << 10));                   // 4KB
    unsigned short* li16 = (unsigned short*)(wsb + (1412 << 10));  // 128KB
    unsigned short* h16v = (unsigned short*)(wsb + (1540 << 10));  // 64KB
    float* gpart = (float*)(wsb + (1604 << 10));                   // 2MB
    unsigned short* h116 = (unsigned short*)(wsb + (3652 << 10));  // 64KB

    hipLaunchKernelGGL(k_pre, dim3(360), dim3(256), 0, stream,
                       hidden, Ws, Wh, pos, Wp, bp, wh16, qs, gate, ctxu, denom);
    hipLaunchKernelGGL(k_scores, dim3(512), dim3(1024), 0, stream,
                       enc, wh16, qs, Vw, gate, mask, part, ctxu, denom);
    hipLaunchKernelGGL(k_fin, dim3(64), dim3(256), 0, stream,
                       part, ctxu, denom, attn, ctx);
    hipLaunchKernelGGL(k_build, dim3(64), dim3(256), 0, stream,
                       tok, embt, ctx, hidden, li16, h16v);
    hipLaunchKernelGGL(k_gates, dim3(64), dim3(256), 0, stream, li16, h16v, Wih, Whh, gpart);
    hipLaunchKernelGGL(k_lstm, dim3(64), dim3(512), 0, stream,
                       gpart, bih, bhh, cell, out_h, out_c, h116);
    hipLaunchKernelGGL(k_pred, dim3(250), dim3(512), 0, stream, h116, Wout, bout, pred);
}

// Round 20
// 170.169 us; speedup vs baseline: 1.0488x; 1.0488x over previous
//
#include <hip/hip_runtime.h>

#define BB 64
#define SS 1024
#define HH 512
#define EE 512
#define VV 32000
#define PP 40

typedef __attribute__((ext_vector_type(8))) __bf16 bf16x8;
typedef __attribute__((ext_vector_type(4))) float f32x4;
typedef __attribute__((ext_vector_type(8))) unsigned short us8_t;
typedef __attribute__((ext_vector_type(4))) unsigned short us4_t;

__device__ inline float fast_tanh(float x) {
    float e = __expf(-2.0f * fabsf(x));
    float t = (1.0f - e) / (1.0f + e);
    return copysignf(t, x);
}
__device__ inline float sigmf(float x) { return 1.0f / (1.0f + __expf(-x)); }

// non-volatile: pure register computation, schedulable/CSE-able (R12 lesson)
__device__ inline unsigned int cvtpk(float lo, float hi) {
    unsigned int r;
    asm("v_cvt_pk_bf16_f32 %0, %1, %2" : "=v"(r) : "v"(lo), "v"(hi));
    return r;
}
__device__ inline us8_t pack8c(float4 x, float4 y) {
    union { unsigned int u[4]; us8_t v; } r;
    r.u[0] = cvtpk(x.x, x.y); r.u[1] = cvtpk(x.z, x.w);
    r.u[2] = cvtpk(y.x, y.y); r.u[3] = cvtpk(y.z, y.w);
    return r.v;
}
__device__ inline us8_t pack8v(f32x4 a, f32x4 b) {
    union { unsigned int u[4]; us8_t v; } r;
    r.u[0] = cvtpk(a[0], a[1]); r.u[1] = cvtpk(a[2], a[3]);
    r.u[2] = cvtpk(b[0], b[1]); r.u[3] = cvtpk(b[2], b[3]);
    return r.v;
}

typedef __attribute__((address_space(1))) const unsigned char gas_t;
typedef __attribute__((address_space(3))) unsigned char las_t;
__device__ inline void gload16(const void* g, void* l) {
    __builtin_amdgcn_global_load_lds((gas_t*)g, (las_t*)l, 16, 0, 0);
}

// ---------------------------------------------------------------------------
// k_pre (concurrent branches): 0..63 qs = hidden @ W_s^T; 64..95 W_h->bf16;
// 96..351 gate = sigmoid(pos_onehot @ W_p + b_p); 352..359 ctx zero.
// ---------------------------------------------------------------------------
__global__ __launch_bounds__(256)
void k_pre(const float* __restrict__ hidden, const float* __restrict__ Ws,
           const float* __restrict__ Wh, const float* __restrict__ pos,
           const float* __restrict__ Wp, const float* __restrict__ bp,
           unsigned short* __restrict__ wh16, float* __restrict__ qs,
           float* __restrict__ gate, float* __restrict__ ctx) {
    int blk = blockIdx.x, t = threadIdx.x;
    if (blk < 64) {
        __shared__ float hb[HH];
        int b = blk;
        for (int i = t; i < HH; i += 256) hb[i] = hidden[b * HH + i];
        __syncthreads();
        for (int n = t; n < HH; n += 256) {
            const float* wr = Ws + (size_t)n * HH;
            float acc = 0.0f;
#pragma unroll 4
            for (int k = 0; k < HH; k += 4) {
                float4 w = *(const float4*)(wr + k);
                acc += w.x * hb[k] + w.y * hb[k + 1] + w.z * hb[k + 2] + w.w * hb[k + 3];
            }
            qs[b * HH + n] = acc;
        }
    } else if (blk < 96) {
        int base = (blk - 64) * 8192 + t * 4;
#pragma unroll
        for (int j = 0; j < 8; ++j) {
            int idx = base + j * 1024;
            float4 x = *(const float4*)(Wh + idx);
            union { unsigned int u[2]; us4_t v; } r;
            r.u[0] = cvtpk(x.x, x.y); r.u[1] = cvtpk(x.z, x.w);
            *(us4_t*)(wh16 + idx) = r.v;
        }
    } else if (blk < 352) {
        int idx = (blk - 96) * 256 + t;  // 0..65535 = b*S+s
        const float* pr = pos + (size_t)idx * PP;
        float acc = bp[0];
#pragma unroll
        for (int j = 0; j < 10; ++j) {
            float4 x = *(const float4*)(pr + j * 4);
            acc += x.x * Wp[j * 4] + x.y * Wp[j * 4 + 1] + x.z * Wp[j * 4 + 2] + x.w * Wp[j * 4 + 3];
        }
        gate[idx] = sigmf(acc);
    } else {
        int idx = (blk - 352) * 256 + t;  // ctx zero
#pragma unroll
        for (int j = 0; j < 16; ++j) ctx[idx * 16 + j] = 0.0f;
    }
}

// ---------------------------------------------------------------------------
// k_scores v10 (champion, 94us measured): C(s,n) = enc(f32) @ wh16^T.
// A staged f32 via global_load_lds, cvtpk after ds_read. 8 waves (2m x 4n),
// tile 128s x 256n, BK=32, 16 K-tiles. Counted vmcnt(4): next tile's stage
// loads stay in flight across barriers; drain only at the last tile.
// Swizzle (rule #21): LDS linear dest, pre-swizzled global source, XOR read.
// grid 1024 = nh(2) x b(64) x sc(8). Epilogue fuses tanh*Vw + n-reduce.
// ---------------------------------------------------------------------------
__global__ __launch_bounds__(512)
void k_scores(const float* __restrict__ enc,
              const unsigned short* __restrict__ wh16,
              const float* __restrict__ qs, const float* __restrict__ Vw,
              float* __restrict__ part) {
    __shared__ float As[2][4096];            // 2 x 16KB: [row(128)][k(32)] f32
    __shared__ unsigned short Bs[2][8192];   // 2 x 16KB: [row(256)][k(32)] bf16
    __shared__ float pbuf[4][128];
    int bid = blockIdx.x;
    int nh = bid >> 9, rest = bid & 511;
    int b = rest >> 3, sc = rest & 7;
    int s0 = sc * 128, n0 = nh * 256;
    int tid = threadIdx.x;
    int w = tid >> 6, lane = tid & 63;
    int wm = w >> 2, wn = w & 3;
    int l15 = lane & 15, lq = lane >> 4;

    float qv[4], vw[4];
#pragma unroll
    for (int nf = 0; nf < 4; ++nf) {
        int n = n0 + wn * 64 + nf * 16 + l15;
        qv[nf] = qs[b * HH + n];
        vw[nf] = Vw[n];
    }

    unsigned int colbA = (unsigned int)(((lane & 7) * 16) ^ ((lane >> 3) << 4));
    unsigned int colbB = (unsigned int)(((lane & 3) * 16) ^ (((lane >> 3) & 3) << 4));
    const char* gA0 = (const char*)(enc + (size_t)(b * SS + s0) * HH);
    const char* gB0 = (const char*)(wh16 + (size_t)n0 * HH);
    int aRowS = w * 8 + (lane >> 3);     // + p*64
    int bRowS = w * 16 + (lane >> 2);    // + p*128
    int ldsOff = w * 1024 + lane * 16;   // + p*8192

    int aRowB[4], akey[4], bRowB[4], bkey[4];
#pragma unroll
    for (int mf = 0; mf < 4; ++mf) {
        int r = wm * 64 + mf * 16 + l15;
        aRowB[mf] = r * 128;
        akey[mf] = (r & 7) << 4;
    }
#pragma unroll
    for (int nf = 0; nf < 4; ++nf) {
        int r = wn * 64 + nf * 16 + l15;
        bRowB[nf] = r * 64;
        bkey[nf] = ((r >> 1) & 3) << 4;
    }

    f32x4 acc[4][4];
#pragma unroll
    for (int mf = 0; mf < 4; ++mf)
#pragma unroll
        for (int nf = 0; nf < 4; ++nf) acc[mf][nf] = (f32x4){0.f, 0.f, 0.f, 0.f};

#define STAGE(BUF, KT)                                                          \
    {                                                                           \
        _Pragma("unroll")                                                       \
        for (int p = 0; p < 2; ++p) {                                           \
            const char* ga = gA0 + (size_t)(p * 64 + aRowS) * 2048 +            \
                             (KT) * 128 + colbA;                                \
            gload16(ga, (char*)As[BUF] + p * 8192 + ldsOff);                    \
            const char* gb = gB0 + (size_t)(p * 128 + bRowS) * 1024 +           \
                             (KT) * 64 + colbB;                                 \
            gload16(gb, (char*)Bs[BUF] + p * 8192 + ldsOff);                    \
        }                                                                       \
    }

#define COMPUTE(BUF)                                                            \
    {                                                                           \
        us8_t af[4], bf[4];                                                     \
        _Pragma("unroll")                                                       \
        for (int mf = 0; mf < 4; ++mf) {                                        \
            const char* pa = (const char*)As[BUF] + aRowB[mf];                  \
            f32x4 a0 = *(const f32x4*)(pa + ((lq * 32) ^ akey[mf]));            \
            f32x4 a1 = *(const f32x4*)(pa + ((lq * 32 + 16) ^ akey[mf]));       \
            af[mf] = pack8v(a0, a1);                                            \
        }                                                                       \
        _Pragma("unroll")                                                       \
        for (int nf = 0; nf < 4; ++nf)                                          \
            bf[nf] = *(const us8_t*)((const char*)Bs[BUF] + bRowB[nf] +         \
                                     ((lq * 16) ^ bkey[nf]));                   \
        _Pragma("unroll")                                                       \
        for (int mf = 0; mf < 4; ++mf)                                          \
            _Pragma("unroll")                                                   \
            for (int nf = 0; nf < 4; ++nf)                                      \
                acc[mf][nf] = __builtin_amdgcn_mfma_f32_16x16x32_bf16(          \
                    __builtin_bit_cast(bf16x8, af[mf]),                         \
                    __builtin_bit_cast(bf16x8, bf[nf]), acc[mf][nf], 0, 0, 0);  \
    }

    STAGE(0, 0);
#pragma unroll
    for (int kt = 0; kt < 16; ++kt) {
        if (kt < 15) {
            STAGE((kt + 1) & 1, kt + 1);
            asm volatile("s_waitcnt vmcnt(4)" ::: "memory");
        } else {
            asm volatile("s_waitcnt vmcnt(0)" ::: "memory");
        }
        __builtin_amdgcn_s_barrier();    // buf[kt&1] fully staged (all waves)
        COMPUTE(kt & 1);
        __builtin_amdgcn_s_barrier();    // all reads done before re-stage
    }
#undef STAGE
#undef COMPUTE

    // epilogue: p(s) = sum_n Vw[n]*tanh(C + qs[n]); reduce over nf + l15 lanes
#pragma unroll
    for (int mf = 0; mf < 4; ++mf)
#pragma unroll
        for (int r = 0; r < 4; ++r) {
            float p = 0.0f;
#pragma unroll
            for (int nf = 0; nf < 4; ++nf)
                p += vw[nf] * fast_tanh(acc[mf][nf][r] + qv[nf]);
            p += __shfl_xor(p, 1, 64);
            p += __shfl_xor(p, 2, 64);
            p += __shfl_xor(p, 4, 64);
            p += __shfl_xor(p, 8, 64);
            if (l15 == 0) pbuf[wn][wm * 64 + mf * 16 + lq * 4 + r] = p;
        }
    __syncthreads();
    if (tid < 128) {
        part[nh * (BB * SS) + b * SS + s0 + tid] =
            pbuf[0][tid] + pbuf[1][tid] + pbuf[2][tid] + pbuf[3][tid];
    }
}

// ---------------------------------------------------------------------------
// k_context (softmax fused, f32 enc): combines 2 n-half partials, redundant
// row denominator, attn write, context accumulation.
// grid 1024 = b(64) x chunk(16); thread owns h-pair (2t, 2t+1).
// ---------------------------------------------------------------------------
__global__ __launch_bounds__(256)
void k_context(const float* __restrict__ enc, const float* __restrict__ part,
               const float* __restrict__ gate, const unsigned char* __restrict__ mask,
               float* __restrict__ attn, float* __restrict__ ctx) {
    int b = blockIdx.x >> 4, chunk = blockIdx.x & 15;
    int s0 = chunk * 64, t = threadIdx.x;
    int w = t >> 6, ln = t & 63;
    float sum = 0.0f;
#pragma unroll
    for (int j = 0; j < 4; ++j) {
        int s = j * 256 + t;
        float raw = part[b * SS + s] + part[BB * SS + b * SS + s];
        float v = mask[b * SS + s] ? -1e30f : raw * gate[b * SS + s];
        sum += __expf(v);
    }
#pragma unroll
    for (int off = 1; off < 64; off <<= 1) sum += __shfl_xor(sum, off, 64);
    __shared__ float sl[4];
    if (ln == 0) sl[w] = sum;
    __syncthreads();
    float inv = 1.0f / (sl[0] + sl[1] + sl[2] + sl[3]);

    __shared__ float aw[64];
    if (t < 64) {
        int s = s0 + t;
        float raw = part[b * SS + s] + part[BB * SS + b * SS + s];
        float v = mask[b * SS + s] ? -1e30f : raw * gate[b * SS + s];
        float a = __expf(v) * inv;
        aw[t] = a;
        attn[b * SS + s] = a;
    }
    __syncthreads();

    const float* eb = enc + ((size_t)(b * SS + s0)) * HH + 2 * t;
    float a0 = 0.f, a1 = 0.f;
#pragma unroll 4
    for (int s = 0; s < 64; ++s) {
        float2 u = *(const float2*)(eb + (size_t)s * HH);
        a0 += aw[s] * u.x;
        a1 += aw[s] * u.y;
    }
    atomicAdd(&ctx[b * HH + 2 * t], a0);
    atomicAdd(&ctx[b * HH + 2 * t + 1], a1);
}

// ---------------------------------------------------------------------------
// k_build: lstm_in_bf16 = [emb | ctx], h_bf16
// ---------------------------------------------------------------------------
__global__ __launch_bounds__(256)
void k_build(const int* __restrict__ tok, const float* __restrict__ embt,
             const float* __restrict__ ctx, const float* __restrict__ hidden,
             unsigned short* __restrict__ li16, unsigned short* __restrict__ h16v) {
    int b = blockIdx.x, t = threadIdx.x;
    const float* er = embt + (size_t)tok[b] * EE;
    for (int i = 2 * t; i < HH; i += 512) {
        *(unsigned int*)(li16 + b * 1024 + i) = cvtpk(er[i], er[i + 1]);
        *(unsigned int*)(li16 + b * 1024 + 512 + i) = cvtpk(ctx[b * HH + i], ctx[b * HH + i + 1]);
        *(unsigned int*)(h16v + b * HH + i) = cvtpk(hidden[b * HH + i], hidden[b * HH + i + 1]);
    }
}

// ---------------------------------------------------------------------------
// k_gates: gpart[ksl] = lstm_in @ W_ih^T + h @ W_hh^T  (K-slice partials)
// grid 64 = 16 n-tiles(128) x 4 k-slices(384).
// ---------------------------------------------------------------------------
__global__ __launch_bounds__(256)
void k_gates(const unsigned short* __restrict__ li16, const unsigned short* __restrict__ h16v,
             const float* __restrict__ Wih, const float* __restrict__ Whh,
             float* __restrict__ gpart) {
    int nt = blockIdx.x >> 2, ksl = blockIdx.x & 3;
    int wave = threadIdx.x >> 6, lane = threadIdx.x & 63;
    int l15 = lane & 15, lq = lane >> 4, k0 = lq * 8;
    int n0w = nt * 128 + wave * 32;
    f32x4 acc[4][2];
#pragma unroll
    for (int mf = 0; mf < 4; ++mf)
#pragma unroll
        for (int nf = 0; nf < 2; ++nf) acc[mf][nf] = (f32x4){0.f, 0.f, 0.f, 0.f};

    for (int ks = 0; ks < 12; ++ks) {
        int kg = ksl * 384 + ks * 32;
        us8_t af[4];
        if (kg < 1024) {
#pragma unroll
            for (int mf = 0; mf < 4; ++mf)
                af[mf] = *(const us8_t*)(li16 + (mf * 16 + l15) * 1024 + kg + k0);
        } else {
#pragma unroll
            for (int mf = 0; mf < 4; ++mf)
                af[mf] = *(const us8_t*)(h16v + (mf * 16 + l15) * 512 + (kg - 1024) + k0);
        }
#pragma unroll
        for (int nf = 0; nf < 2; ++nf) {
            int n = n0w + nf * 16 + l15;
            us8_t bu;
            if (kg < 1024) {
                const float* wr = Wih + (size_t)n * 1024 + kg + k0;
                bu = pack8c(*(const float4*)wr, *(const float4*)(wr + 4));
            } else {
                const float* wr = Whh + (size_t)n * 512 + (kg - 1024) + k0;
                bu = pack8c(*(const float4*)wr, *(const float4*)(wr + 4));
            }
#pragma unroll
            for (int mf = 0; mf < 4; ++mf)
                acc[mf][nf] = __builtin_amdgcn_mfma_f32_16x16x32_bf16(
                    __builtin_bit_cast(bf16x8, af[mf]),
                    __builtin_bit_cast(bf16x8, bu), acc[mf][nf], 0, 0, 0);
        }
    }
#pragma unroll
    for (int mf = 0; mf < 4; ++mf)
#pragma unroll
        for (int nf = 0; nf < 2; ++nf)
#pragma unroll
            for (int r = 0; r < 4; ++r) {
                int row = mf * 16 + lq * 4 + r;
                int n = n0w + nf * 16 + l15;
                gpart[ksl * (BB * 2048) + row * 2048 + n] = acc[mf][nf][r];
            }
}

// ---------------------------------------------------------------------------
// k_lstm: sum K-slice partials + biases, pointwise cell update
// ---------------------------------------------------------------------------
__global__ __launch_bounds__(512)
void k_lstm(const float* __restrict__ gpart, const float* __restrict__ bih,
            const float* __restrict__ bhh, const float* __restrict__ cell,
            float* __restrict__ oh, float* __restrict__ oc,
            unsigned short* __restrict__ h116) {
    int b = blockIdx.x, t = threadIdx.x;
    float gi = bih[t] + bhh[t];
    float gf = bih[512 + t] + bhh[512 + t];
    float gg = bih[1024 + t] + bhh[1024 + t];
    float go = bih[1536 + t] + bhh[1536 + t];
#pragma unroll
    for (int ksl = 0; ksl < 4; ++ksl) {
        const float* gp = gpart + ksl * (BB * 2048) + b * 2048;
        gi += gp[t];
        gf += gp[512 + t];
        gg += gp[1024 + t];
        go += gp[1536 + t];
    }
    float c0 = cell[b * HH + t];
    float c1 = sigmf(gf) * c0 + sigmf(gi) * fast_tanh(gg);
    float h1 = sigmf(go) * fast_tanh(c1);
    oh[b * HH + t] = h1;
    oc[b * HH + t] = c1;
    h116[b * HH + t] = (unsigned short)(cvtpk(h1, h1) & 0xffffu);
}

// ---------------------------------------------------------------------------
// k_pred: pred = h1 @ W_out^T + b_out  (M=64, N=32000, K=512)
// ---------------------------------------------------------------------------
__global__ __launch_bounds__(512)
void k_pred(const unsigned short* __restrict__ h116, const float* __restrict__ Wout,
            const float* __restrict__ bout, float* __restrict__ pred) {
    int wave = threadIdx.x >> 6, lane = threadIdx.x & 63;
    int l15 = lane & 15, lq = lane >> 4, k0 = lq * 8;
    int n = blockIdx.x * 128 + wave * 16 + l15;
    f32x4 acc[4];
#pragma unroll
    for (int mf = 0; mf < 4; ++mf) acc[mf] = (f32x4){0.f, 0.f, 0.f, 0.f};
    const float* wr = Wout + (size_t)n * HH;
#pragma unroll 4
    for (int ks = 0; ks < 16; ++ks) {
        float4 x = *(const float4*)(wr + ks * 32 + k0);
        float4 y = *(const float4*)(wr + ks * 32 + k0 + 4);
        us8_t bu = pack8c(x, y);
#pragma unroll
        for (int mf = 0; mf < 4; ++mf) {
            us8_t au = *(const us8_t*)(h116 + (mf * 16 + l15) * 512 + ks * 32 + k0);
            acc[mf] = __builtin_amdgcn_mfma_f32_16x16x32_bf16(
                __builtin_bit_cast(bf16x8, au),
                __builtin_bit_cast(bf16x8, bu), acc[mf], 0, 0, 0);
        }
    }
    float bo = bout[n];
#pragma unroll
    for (int mf = 0; mf < 4; ++mf)
#pragma unroll
        for (int r = 0; r < 4; ++r) {
            int row = mf * 16 + lq * 4 + r;
            pred[(size_t)row * VV + n] = acc[mf][r] + bo;
        }
}

// ---------------------------------------------------------------------------
extern "C" void kernel_launch(void* const* d_in, const int* in_sizes, int n_in,
                              void* d_out, int out_size, void* d_ws, size_t ws_size,
                              hipStream_t stream) {
    const int* tok = (const int*)d_in[0];
    const float* hidden = (const float*)d_in[1];
    const float* cell = (const float*)d_in[2];
    const float* enc = (const float*)d_in[3];
    const float* pos = (const float*)d_in[4];
    const unsigned char* mask = (const unsigned char*)d_in[5];
    const float* embt = (const float*)d_in[6];
    const float* Ws = (const float*)d_in[7];
    const float* Wh = (const float*)d_in[8];
    const float* Vw = (const float*)d_in[9];
    const float* Wp = (const float*)d_in[10];
    const float* bp = (const float*)d_in[11];
    const float* Wih = (const float*)d_in[12];
    const float* Whh = (const float*)d_in[13];
    const float* bih = (const float*)d_in[14];
    const float* bhh = (const float*)d_in[15];
    const float* Wout = (const float*)d_in[16];
    const float* bout = (const float*)d_in[17];

    float* out = (float*)d_out;
    float* pred = out;                  // 64*32000
    float* out_h = out + 2048000;       // 64*512
    float* out_c = out + 2080768;       // 64*512
    float* attn = out + 2113536;        // 64*1024

    char* wsb = (char*)d_ws;
    unsigned short* wh16 = (unsigned short*)(wsb);                 // 512KB @0
    float* qs = (float*)(wsb + (512 << 10));                       // 128KB
    float* gate = (float*)(wsb + (640 << 10));                     // 256KB
    float* part = (float*)(wsb + (896 << 10));                     // 512KB (2 slabs)
    float* ctx = (float*)(wsb + (1408 << 10));                     // 128KB
    unsigned short* li16 = (unsigned short*)(wsb + (1536 << 10));  // 128KB
    unsigned short* h16v = (unsigned short*)(wsb + (1664 << 10));  // 64KB
    float* gpart = (float*)(wsb + (1728 << 10));                   // 2MB
    unsigned short* h116 = (unsigned short*)(wsb + (3776 << 10));  // 64KB

    hipLaunchKernelGGL(k_pre, dim3(360), dim3(256), 0, stream,
                       hidden, Ws, Wh, pos, Wp, bp, wh16, qs, gate, ctx);
    hipLaunchKernelGGL(k_scores, dim3(1024), dim3(512), 0, stream,
                       enc, wh16, qs, Vw, part);
    hipLaunchKernelGGL(k_context, dim3(1024), dim3(256), 0, stream,
                       enc, part, gate, mask, attn, ctx);
    hipLaunchKernelGGL(k_build, dim3(64), dim3(256), 0, stream,
                       tok, embt, ctx, hidden, li16, h16v);
    hipLaunchKernelGGL(k_gates, dim3(64), dim3(256), 0, stream, li16, h16v, Wih, Whh, gpart);
    hipLaunchKernelGGL(k_lstm, dim3(64), dim3(512), 0, stream,
                       gpart, bih, bhh, cell, out_h, out_c, h116);
    hipLaunchKernelGGL(k_pred, dim3(250), dim3(512), 0, stream, h116, Wout, bout, pred);
}